// Round 5
// baseline (15698.701 us; speedup 1.0000x reference)
//
#include <hip/hip_runtime.h>
#include <hip/hip_bf16.h>

#define B_ 256
#define T_ 256
#define I_ 512
#define H_ 1024

typedef _Float16 half8 __attribute__((ext_vector_type(8)));
typedef _Float16 half4 __attribute__((ext_vector_type(4)));
typedef float floatx4 __attribute__((ext_vector_type(4)));

__device__ __forceinline__ float fsig(float x) { return 1.f / (1.f + __expf(-x)); }
__device__ __forceinline__ float ftanh(float x) { return 1.f - 2.f / (__expf(2.f * x) + 1.f); }

// Permuted gate-row order: n' -> orig row g*H + h, g=(n'&63)>>4, h=(n'>>6)*16+(n'&15).
// 64-col slice = 16 h-units x 4 gates; gates of unit (lane&15) land in same lane.

__global__ __launch_bounds__(256) void prep_w(
    _Float16* __restrict__ dst, const float* __restrict__ src, int K) {
  const int np = blockIdx.y;
  const int k = blockIdx.x * 256 + threadIdx.x;
  const int cc = np & 63, g = cc >> 4, j = cc & 15;
  const int orig = g * H_ + (np >> 6) * 16 + j;
  dst[(size_t)np * K + k] = (_Float16)src[(size_t)orig * K + k];
}

__global__ __launch_bounds__(256) void prep_bias(
    float* __restrict__ bs0, float* __restrict__ bs1,
    const float* __restrict__ bih0, const float* __restrict__ bhh0,
    const float* __restrict__ bih1, const float* __restrict__ bhh1) {
  const int np = blockIdx.x * 256 + threadIdx.x;   // grid 16
  const int cc = np & 63, g = cc >> 4, j = cc & 15;
  const int orig = g * H_ + (np >> 6) * 16 + j;
  bs0[np] = bih0[orig] + bhh0[orig];
  bs1[np] = bih1[orig] + bhh1[orig];
}

struct MegaArgs {
  const float* ctx;
  const _Float16* W0p;  const _Float16* W1p;
  const _Float16* Wh0p; const _Float16* Wh1p;
  const float* bs0; const float* bs1;
  _Float16* h1ring; _Float16* h2ring;     // [2][B_*H_]
  _Float16* xg0ring; _Float16* xg1ring;   // [2][B_*4096]
  float* hF;
  const float* init;
  unsigned* bar;                          // [cnt, gen]
};

// Device-scope sense-reversing grid barrier (256 blocks, 1/CU -> all resident).
__device__ __forceinline__ void gridbar(unsigned* bar) {
  __syncthreads();
  if (threadIdx.x == 0) {
    unsigned* cnt = bar;
    unsigned* gen = bar + 16;   // separate cache lines
    unsigned g = __hip_atomic_load(gen, __ATOMIC_RELAXED, __HIP_MEMORY_SCOPE_AGENT);
    unsigned a = __hip_atomic_fetch_add(cnt, 1u, __ATOMIC_ACQ_REL, __HIP_MEMORY_SCOPE_AGENT);
    if (a == 255u) {
      __hip_atomic_store(cnt, 0u, __ATOMIC_RELAXED, __HIP_MEMORY_SCOPE_AGENT);
      __hip_atomic_store(gen, g + 1u, __ATOMIC_RELEASE, __HIP_MEMORY_SCOPE_AGENT);
    } else {
      while (__hip_atomic_load(gen, __ATOMIC_ACQUIRE, __HIP_MEMORY_SCOPE_AGENT) == g)
        __builtin_amdgcn_s_sleep(1);
    }
  }
  __syncthreads();
}

// GEMM tile: 128 rows x 64 cols (wave w = cols w*16..+16, all 128 rows), B in regs.
// AMODE 0: A fp32 (ctx), AMODE 1: A f16. aptr pre-offset to (row, scol) in elements.
template<int NC, int AMODE>
__device__ __forceinline__ void gemm_tile(
    const void* __restrict__ aptr, const half8* __restrict__ bf,
    _Float16* __restrict__ ab, floatx4 (&gacc)[8]) {
  const int tid = threadIdx.x;
  const int srow = tid >> 1;
  const int lane = tid & 63, l15 = lane & 15, l4 = lane >> 4;
  const float*    af32 = (const float*)aptr;
  const _Float16* af16 = (const _Float16*)aptr;
  half8 st[2][4];
  auto fetch = [&](int c, int slot) {
    #pragma unroll
    for (int p = 0; p < 4; ++p) {
      if (AMODE == 0) {
        float4 f0 = *(const float4*)(af32 + c * 64 + p * 8);
        float4 f1 = *(const float4*)(af32 + c * 64 + p * 8 + 4);
        half8 h;
        h[0] = (_Float16)f0.x; h[1] = (_Float16)f0.y;
        h[2] = (_Float16)f0.z; h[3] = (_Float16)f0.w;
        h[4] = (_Float16)f1.x; h[5] = (_Float16)f1.y;
        h[6] = (_Float16)f1.z; h[7] = (_Float16)f1.w;
        st[slot][p] = h;
      } else {
        st[slot][p] = *(const half8*)(af16 + c * 64 + p * 8);
      }
    }
  };
  fetch(0, 0);
  fetch(1, 1);
  #pragma unroll
  for (int c = 0; c < NC; ++c) {
    __syncthreads();
    #pragma unroll
    for (int p = 0; p < 4; ++p) {
      const int g = (tid & 1) * 4 + p;
      *(half8*)(ab + srow * 64 + ((g ^ (srow & 7)) * 8)) = st[c & 1][p];
    }
    __syncthreads();
    if (c + 2 < NC) fetch(c + 2, c & 1);
    #pragma unroll
    for (int ks2 = 0; ks2 < 2; ++ks2) {
      #pragma unroll
      for (int m = 0; m < 8; ++m) {
        const int arow = m * 16 + l15;
        const int ga = ks2 * 4 + l4;
        half8 af = *(const half8*)(ab + arow * 64 + ((ga ^ (arow & 7)) * 8));
        gacc[m] = __builtin_amdgcn_mfma_f32_16x16x32_f16(af, bf[c * 2 + ks2], gacc[m], 0, 0, 0);
      }
    }
  }
}

// Persistent fused kernel: 256 blocks (1/CU). bid>>7=layer, (bid>>6)&1=strip, bid&63=colblock.
// Schedule: L0-rec t0=s-1 (1..256); L0-gemm xg0[t=s] (0..255);
//           L1-gemm xg1[tau=s-2] (2..257); L1-rec t1=s-3 (3..258). Rings depth 2.
__global__ __launch_bounds__(256, 1) void mega(MegaArgs a) {
  const int bid = blockIdx.x, tid = threadIdx.x;
  const int layer = bid >> 7, strip = (bid >> 6) & 1, nb = bid & 63;
  const int row0 = strip * 128;
  const int w = tid >> 6, lane = tid & 63, l15 = lane & 15, l4 = lane >> 4;

  __shared__ _Float16 whb[64 * 1024];   // 128 KB: resident W_hh slice (swizzled)
  __shared__ _Float16 ab[128 * 64];     // 16 KB: A-chunk (swizzled)

  // ---- init h rings (slot 1 = t=-1 state) ----
  {
    const int idx = (bid * 256 + tid) * 4;
    const float4 v = *(const float4*)(a.init + idx);
    half4 hv; hv[0] = (_Float16)v.x; hv[1] = (_Float16)v.y;
    hv[2] = (_Float16)v.z; hv[3] = (_Float16)v.w;
    *(half4*)(a.h1ring + B_ * H_ + idx) = hv;
    *(half4*)(a.h2ring + B_ * H_ + idx) = hv;
  }

  // ---- stage resident W_hh slice -> LDS (swizzled granules) ----
  {
    const _Float16* Whp = (layer ? a.Wh1p : a.Wh0p) + (size_t)nb * 64 * 1024;
    const int row = tid & 63;
    const int gb = (tid >> 6) * 32;
    #pragma unroll
    for (int i = 0; i < 32; ++i) {
      const int g = gb + i;
      half8 v = *(const half8*)(Whp + (size_t)row * 1024 + g * 8);
      *(half8*)(whb + row * 1024 + ((g ^ (row & 7)) * 8)) = v;
    }
  }

  // ---- GEMM B-fragments -> registers ----
  const _Float16* Wg = layer ? a.W1p : a.W0p;
  const int gK = layer ? 1024 : 512;
  const int gcol = nb * 64 + w * 16 + l15;
  half8 bf[32];
  {
    const int nks = layer ? 32 : 16;
    #pragma unroll
    for (int ks = 0; ks < 32; ++ks)
      if (ks < nks)
        bf[ks] = *(const half8*)(Wg + (size_t)gcol * gK + ks * 32 + l4 * 8);
  }
  const float bv = (layer ? a.bs1 : a.bs0)[gcol];

  float cst[8] = {0.f, 0.f, 0.f, 0.f, 0.f, 0.f, 0.f, 0.f};
  const int hu = nb * 16 + l15;
  const int srow = tid >> 1;
  const int scol = (tid & 1) * 32;

  for (int s = 0; s <= 258; ++s) {
    gridbar(a.bar);
    // ================= recurrent (h @ W_hh, K=1024, LDS-resident B) =================
    const bool recAct = layer ? (s >= 3 && s <= 258) : (s >= 1 && s <= 256);
    if (recAct) {
      const _Float16* Asrc = (layer ? a.h2ring : a.h1ring) + (size_t)(s & 1) * (B_ * H_);
      const _Float16* xg = (layer ? a.xg1ring : a.xg0ring) + (size_t)((s - 1) & 1) * (B_ * 4096);
      const _Float16* abase = Asrc + (size_t)(row0 + srow) * H_ + scol;
      floatx4 racc[2][4] = {};
      half8 st[2][4];
      #pragma unroll
      for (int p = 0; p < 4; ++p) st[0][p] = *(const half8*)(abase + 0 * 64 + p * 8);
      #pragma unroll
      for (int p = 0; p < 4; ++p) st[1][p] = *(const half8*)(abase + 1 * 64 + p * 8);
      #pragma unroll
      for (int c = 0; c < 16; ++c) {
        __syncthreads();
        #pragma unroll
        for (int p = 0; p < 4; ++p) {
          const int g = (tid & 1) * 4 + p;
          *(half8*)(ab + srow * 64 + ((g ^ (srow & 7)) * 8)) = st[c & 1][p];
        }
        __syncthreads();
        if (c + 2 < 16) {
          #pragma unroll
          for (int p = 0; p < 4; ++p)
            st[c & 1][p] = *(const half8*)(abase + (c + 2) * 64 + p * 8);
        }
        #pragma unroll
        for (int ks2 = 0; ks2 < 2; ++ks2) {
          half8 wbf[4];
          #pragma unroll
          for (int n = 0; n < 4; ++n) {
            const int wrow = n * 16 + l15;
            const int g = c * 8 + ks2 * 4 + l4;
            wbf[n] = *(const half8*)(whb + wrow * 1024 + ((g ^ (wrow & 7)) * 8));
          }
          #pragma unroll
          for (int m = 0; m < 2; ++m) {
            const int arow = w * 32 + m * 16 + l15;
            const int ga = ks2 * 4 + l4;
            half8 af = *(const half8*)(ab + arow * 64 + ((ga ^ (arow & 7)) * 8));
            #pragma unroll
            for (int n = 0; n < 4; ++n)
              racc[m][n] = __builtin_amdgcn_mfma_f32_16x16x32_f16(af, wbf[n], racc[m][n], 0, 0, 0);
          }
        }
      }
      // ---- register-local cell update ----
      const int t = layer ? (s - 3) : (s - 1);
      _Float16* hw = (layer ? a.h2ring : a.h1ring) + (size_t)((s - 1) & 1) * (B_ * H_);
      #pragma unroll
      for (int m = 0; m < 2; ++m) {
        #pragma unroll
        for (int r = 0; r < 4; ++r) {
          const int brow = row0 + w * 32 + m * 16 + l4 * 4 + r;
          const _Float16* xr = xg + (size_t)brow * 4096 + nb * 64;
          const float gi = racc[m][0][r] + (float)xr[l15];
          const float gf = racc[m][1][r] + (float)xr[16 + l15];
          const float gg = racc[m][2][r] + (float)xr[32 + l15];
          const float go = racc[m][3][r] + (float)xr[48 + l15];
          const float si = fsig(gi), sf = fsig(gf), so = fsig(go);
          const float tg = ftanh(gg);
          const float cn = sf * cst[m * 4 + r] + si * tg;
          const float hn = so * ftanh(cn);
          cst[m * 4 + r] = cn;
          hw[(size_t)brow * H_ + hu] = (_Float16)hn;
          if (layer == 1 && t == 255) a.hF[(size_t)brow * H_ + hu] = hn;
        }
      }
    }
    __syncthreads();
    // ================= input-GEMM slice (B in regs) =================
    const bool gAct = layer ? (s >= 2 && s <= 257) : (s <= 255);
    if (gAct) {
      _Float16* og = (layer ? a.xg1ring : a.xg0ring) + (size_t)(s & 1) * (B_ * 4096);
      floatx4 gacc[8] = {};
      if (layer) {
        const _Float16* abase = a.h1ring + (size_t)(s & 1) * (B_ * H_)
                              + (size_t)(row0 + srow) * H_ + scol;
        gemm_tile<16, 1>(abase, bf, ab, gacc);
      } else {
        const float* abase = a.ctx + ((size_t)(row0 + srow) * T_ + s) * I_ + scol;
        gemm_tile<8, 0>(abase, bf, ab, gacc);
      }
      #pragma unroll
      for (int m = 0; m < 8; ++m) {
        #pragma unroll
        for (int r = 0; r < 4; ++r)
          og[(size_t)(row0 + m * 16 + l4 * 4 + r) * 4096 + gcol] = (_Float16)(gacc[m][r] + bv);
      }
    }
  }
}

__global__ __launch_bounds__(256) void readout(
    const float* __restrict__ hF, const float* __restrict__ Wro,
    const float* __restrict__ bro, float* __restrict__ out) {
  const int b = blockIdx.x;
  const int tid = threadIdx.x;
  float p = 0.f;
  for (int h = tid; h < H_; h += 256) p += hF[(size_t)b * H_ + h] * Wro[h];
  #pragma unroll
  for (int off = 32; off; off >>= 1) p += __shfl_down(p, off, 64);
  __shared__ float red[4];
  if ((tid & 63) == 0) red[tid >> 6] = p;
  __syncthreads();
  if (tid == 0) out[b] = red[0] + red[1] + red[2] + red[3] + bro[0];
}

extern "C" void kernel_launch(void* const* d_in, const int* in_sizes, int n_in,
                              void* d_out, int out_size, void* d_ws, size_t ws_size,
                              hipStream_t stream) {
  const float* init_hidden = (const float*)d_in[0];
  const float* ctx   = (const float*)d_in[1];
  const float* W_ih0 = (const float*)d_in[2];
  const float* W_hh0 = (const float*)d_in[3];
  const float* b_ih0 = (const float*)d_in[4];
  const float* b_hh0 = (const float*)d_in[5];
  const float* W_ih1 = (const float*)d_in[6];
  const float* W_hh1 = (const float*)d_in[7];
  const float* b_ih1 = (const float*)d_in[8];
  const float* b_hh1 = (const float*)d_in[9];
  const float* W_ro  = (const float*)d_in[10];
  const float* b_ro  = (const float*)d_in[11];

  char* ws = (char*)d_ws;
  const size_t MB = 1 << 20;
  _Float16* W0p    = (_Float16*)(ws);                      // 4 MiB
  _Float16* Wh0p   = (_Float16*)(ws + 4 * MB);             // 8 MiB
  _Float16* W1p    = (_Float16*)(ws + 12 * MB);            // 8 MiB
  _Float16* Wh1p   = (_Float16*)(ws + 20 * MB);            // 8 MiB
  float*    bs0    = (float*)(ws + 28 * MB);               // 16 KiB
  float*    bs1    = (float*)(ws + 28 * MB + 16384);       // 16 KiB
  float*    hF     = (float*)(ws + 28 * MB + 32768);       // 1 MiB
  _Float16* h1ring = (_Float16*)(ws + 29 * MB + 32768);    // 1 MiB (2 slots)
  _Float16* h2ring = (_Float16*)(ws + 30 * MB + 32768);    // 1 MiB
  _Float16* xg0    = (_Float16*)(ws + 31 * MB + 32768);    // 4 MiB (2 slots)
  _Float16* xg1    = (_Float16*)(ws + 35 * MB + 32768);    // 4 MiB
  unsigned* bar    = (unsigned*)(ws + 39 * MB + 32768);    // 128 B -> end ~39.03 MiB

  hipMemsetAsync(bar, 0, 128, stream);
  prep_w<<<dim3(2, 4096), 256, 0, stream>>>(W0p, W_ih0, 512);
  prep_w<<<dim3(4, 4096), 256, 0, stream>>>(Wh0p, W_hh0, 1024);
  prep_w<<<dim3(4, 4096), 256, 0, stream>>>(W1p, W_ih1, 1024);
  prep_w<<<dim3(4, 4096), 256, 0, stream>>>(Wh1p, W_hh1, 1024);
  prep_bias<<<dim3(16), 256, 0, stream>>>(bs0, bs1, b_ih0, b_hh0, b_ih1, b_hh1);

  MegaArgs ma;
  ma.ctx = ctx; ma.W0p = W0p; ma.W1p = W1p; ma.Wh0p = Wh0p; ma.Wh1p = Wh1p;
  ma.bs0 = bs0; ma.bs1 = bs1; ma.h1ring = h1ring; ma.h2ring = h2ring;
  ma.xg0ring = xg0; ma.xg1ring = xg1; ma.hF = hF; ma.init = init_hidden;
  ma.bar = bar;
  mega<<<dim3(256), dim3(256), 0, stream>>>(ma);

  readout<<<dim3(256), 256, 0, stream>>>(hF, W_ro, b_ro, (float*)d_out);
}

// Round 6
// 7074.360 us; speedup vs baseline: 2.2191x; 2.2191x over previous
//
#include <hip/hip_runtime.h>
#include <hip/hip_bf16.h>

#define B_ 256
#define T_ 256
#define I_ 512
#define H_ 1024

typedef _Float16 half8 __attribute__((ext_vector_type(8)));
typedef float floatx4 __attribute__((ext_vector_type(4)));

__device__ __forceinline__ float fsig(float x) { return 1.f / (1.f + __expf(-x)); }
__device__ __forceinline__ float ftanh(float x) { return 1.f - 2.f / (__expf(2.f * x) + 1.f); }

// agent-scope write-through f16 store (visible cross-XCD at L3 without L2 flush)
__device__ __forceinline__ void st_h16(_Float16* p, _Float16 v) {
  unsigned short u = __builtin_bit_cast(unsigned short, v);
  __hip_atomic_store((unsigned short*)p, u, __ATOMIC_RELAXED, __HIP_MEMORY_SCOPE_AGENT);
}

// Permuted gate-row order: n' -> orig row g*H + h, g=(n'&63)>>4, h=(n'>>6)*16+(n'&15).

__global__ __launch_bounds__(256) void prep_w(
    _Float16* __restrict__ dst, const float* __restrict__ src, int K) {
  const int np = blockIdx.y;
  const int k = blockIdx.x * 256 + threadIdx.x;
  const int cc = np & 63, g = cc >> 4, j = cc & 15;
  const int orig = g * H_ + (np >> 6) * 16 + j;
  dst[(size_t)np * K + k] = (_Float16)src[(size_t)orig * K + k];
}

__global__ __launch_bounds__(256) void prep_bias(
    float* __restrict__ bs0, float* __restrict__ bs1,
    const float* __restrict__ bih0, const float* __restrict__ bhh0,
    const float* __restrict__ bih1, const float* __restrict__ bhh1) {
  const int np = blockIdx.x * 256 + threadIdx.x;   // grid 16
  const int cc = np & 63, g = cc >> 4, j = cc & 15;
  const int orig = g * H_ + (np >> 6) * 16 + j;
  bs0[np] = bih0[orig] + bhh0[orig];
  bs1[np] = bih1[orig] + bhh1[orig];
}

struct MegaArgs {
  const float* ctx;
  const _Float16* W0p;  const _Float16* W1p;
  const _Float16* Wh0p; const _Float16* Wh1p;
  const float* bs0; const float* bs1;
  _Float16* h1ring; _Float16* h2ring;     // [2][B_*H_]
  _Float16* xg0ring; _Float16* xg1ring;   // [2][B_*4096] (block-local, L2-resident)
  float* hF;
  const float* init;
  unsigned* flags;                        // [256] progress flags, flags[bid]=steps done
};

// Publish: all block's prior stores drained by __syncthreads (compiler emits
// vmcnt(0) before s_barrier), then one relaxed agent flag store.
__device__ __forceinline__ void publish(unsigned* flags, int bid, unsigned v) {
  __syncthreads();
  if (threadIdx.x == 0) {
    asm volatile("" ::: "memory");
    __hip_atomic_store(&flags[bid], v, __ATOMIC_RELAXED, __HIP_MEMORY_SCOPE_AGENT);
  }
}

// Wait until all 128 blocks of this strip (both layers) have published >= tgt.
__device__ __forceinline__ void wait_strip(unsigned* flags, int strip, unsigned tgt) {
  if (threadIdx.x < 64) {
    unsigned* f0 = flags + strip * 64 + threadIdx.x;         // layer-0 group
    unsigned* f1 = flags + 128 + strip * 64 + threadIdx.x;   // layer-1 group
    for (;;) {
      const unsigned a = __hip_atomic_load(f0, __ATOMIC_RELAXED, __HIP_MEMORY_SCOPE_AGENT);
      const unsigned b = __hip_atomic_load(f1, __ATOMIC_RELAXED, __HIP_MEMORY_SCOPE_AGENT);
      if (__all(a >= tgt && b >= tgt)) break;
      __builtin_amdgcn_s_sleep(1);
    }
    __builtin_amdgcn_fence(__ATOMIC_ACQUIRE, "agent");   // buffer_inv: see remote h-writes
  }
  __syncthreads();
}

// GEMM tile: 128 rows x 64 cols (wave w = cols w*16..+16, all 128 rows), B in regs.
// AMODE 0: A fp32 (ctx), AMODE 1: A f16. aptr pre-offset to (row, scol) in elements.
template<int NC, int AMODE>
__device__ __forceinline__ void gemm_tile(
    const void* __restrict__ aptr, const half8* __restrict__ bf,
    _Float16* __restrict__ ab, floatx4 (&gacc)[8]) {
  const int tid = threadIdx.x;
  const int srow = tid >> 1;
  const int lane = tid & 63, l15 = lane & 15, l4 = lane >> 4;
  const float*    af32 = (const float*)aptr;
  const _Float16* af16 = (const _Float16*)aptr;
  half8 st[2][4];
  auto fetch = [&](int c, int slot) {
    #pragma unroll
    for (int p = 0; p < 4; ++p) {
      if (AMODE == 0) {
        float4 f0 = *(const float4*)(af32 + c * 64 + p * 8);
        float4 f1 = *(const float4*)(af32 + c * 64 + p * 8 + 4);
        half8 h;
        h[0] = (_Float16)f0.x; h[1] = (_Float16)f0.y;
        h[2] = (_Float16)f0.z; h[3] = (_Float16)f0.w;
        h[4] = (_Float16)f1.x; h[5] = (_Float16)f1.y;
        h[6] = (_Float16)f1.z; h[7] = (_Float16)f1.w;
        st[slot][p] = h;
      } else {
        st[slot][p] = *(const half8*)(af16 + c * 64 + p * 8);
      }
    }
  };
  fetch(0, 0);
  fetch(1, 1);
  #pragma unroll
  for (int c = 0; c < NC; ++c) {
    __syncthreads();
    #pragma unroll
    for (int p = 0; p < 4; ++p) {
      const int g = (tid & 1) * 4 + p;
      *(half8*)(ab + srow * 64 + ((g ^ (srow & 7)) * 8)) = st[c & 1][p];
    }
    __syncthreads();
    if (c + 2 < NC) fetch(c + 2, c & 1);
    #pragma unroll
    for (int ks2 = 0; ks2 < 2; ++ks2) {
      #pragma unroll
      for (int m = 0; m < 8; ++m) {
        const int arow = m * 16 + l15;
        const int ga = ks2 * 4 + l4;
        half8 af = *(const half8*)(ab + arow * 64 + ((ga ^ (arow & 7)) * 8));
        gacc[m] = __builtin_amdgcn_mfma_f32_16x16x32_f16(af, bf[c * 2 + ks2], gacc[m], 0, 0, 0);
      }
    }
  }
}

// Persistent fused kernel: 256 blocks (1/CU). bid>>7=layer, (bid>>6)&1=strip, bid&63=colblock.
// Schedule: L0-rec t=s-1 (s:1..256); L0-gemm xg0[t=s] (s:0..255);
//           L1-gemm tau=s-2 (s:2..257); L1-rec t=s-3 (s:3..258). Rings depth 2.
// Sync: per-strip flag barrier; G0 publishes after rec, G1 after rec+gemm.
__global__ __launch_bounds__(256, 1) void mega(MegaArgs a) {
  const int bid = blockIdx.x, tid = threadIdx.x;
  const int layer = bid >> 7, strip = (bid >> 6) & 1, nb = bid & 63;
  const int row0 = strip * 128;
  const int w = tid >> 6, lane = tid & 63, l15 = lane & 15, l4 = lane >> 4;

  __shared__ _Float16 whb[64 * 1024];   // 128 KB: resident W_hh slice (swizzled)
  __shared__ _Float16 ab[128 * 64];     // 16 KB: A-chunk (swizzled)

  // ---- init h rings (slot 1 = t=-1 state), write-through ----
  {
    const int idx = (bid * 256 + tid) * 4;
    const float4 v = *(const float4*)(a.init + idx);
    st_h16(a.h1ring + B_ * H_ + idx,     (_Float16)v.x);
    st_h16(a.h1ring + B_ * H_ + idx + 1, (_Float16)v.y);
    st_h16(a.h1ring + B_ * H_ + idx + 2, (_Float16)v.z);
    st_h16(a.h1ring + B_ * H_ + idx + 3, (_Float16)v.w);
    st_h16(a.h2ring + B_ * H_ + idx,     (_Float16)v.x);
    st_h16(a.h2ring + B_ * H_ + idx + 1, (_Float16)v.y);
    st_h16(a.h2ring + B_ * H_ + idx + 2, (_Float16)v.z);
    st_h16(a.h2ring + B_ * H_ + idx + 3, (_Float16)v.w);
  }

  // ---- stage resident W_hh slice -> LDS (swizzled granules) ----
  {
    const _Float16* Whp = (layer ? a.Wh1p : a.Wh0p) + (size_t)nb * 64 * 1024;
    const int row = tid & 63;
    const int gb = (tid >> 6) * 32;
    #pragma unroll
    for (int i = 0; i < 32; ++i) {
      const int g = gb + i;
      half8 v = *(const half8*)(Whp + (size_t)row * 1024 + g * 8);
      *(half8*)(whb + row * 1024 + ((g ^ (row & 7)) * 8)) = v;
    }
  }

  // ---- GEMM B-fragments -> registers ----
  const _Float16* Wg = layer ? a.W1p : a.W0p;
  const int gK = layer ? 1024 : 512;
  const int gcol = nb * 64 + w * 16 + l15;
  half8 bf[32];
  {
    const int nks = layer ? 32 : 16;
    #pragma unroll
    for (int ks = 0; ks < 32; ++ks)
      if (ks < nks)
        bf[ks] = *(const half8*)(Wg + (size_t)gcol * gK + ks * 32 + l4 * 8);
  }
  const float bv = (layer ? a.bs1 : a.bs0)[gcol];

  float cst[8] = {0.f, 0.f, 0.f, 0.f, 0.f, 0.f, 0.f, 0.f};
  const int hu = nb * 16 + l15;
  const int srow = tid >> 1;
  const int scol = (tid & 1) * 32;

  publish(a.flags, bid, 1u);   // init done

  for (int s = 0; s <= 258; ++s) {
    wait_strip(a.flags, strip, (unsigned)(s + 1));

    // ================= recurrent (h @ W_hh, K=1024, LDS-resident B) =================
    const bool recAct = layer ? (s >= 3 && s <= 258) : (s >= 1 && s <= 256);
    if (recAct) {
      const _Float16* Asrc = (layer ? a.h2ring : a.h1ring) + (size_t)(s & 1) * (B_ * H_);
      const _Float16* xg = (layer ? a.xg1ring : a.xg0ring) + (size_t)((s - 1) & 1) * (B_ * 4096);
      const _Float16* abase = Asrc + (size_t)(row0 + srow) * H_ + scol;
      floatx4 racc[2][4] = {};
      half8 st[2][4];
      #pragma unroll
      for (int p = 0; p < 4; ++p) st[0][p] = *(const half8*)(abase + 0 * 64 + p * 8);
      #pragma unroll
      for (int p = 0; p < 4; ++p) st[1][p] = *(const half8*)(abase + 1 * 64 + p * 8);
      #pragma unroll
      for (int c = 0; c < 16; ++c) {
        __syncthreads();
        #pragma unroll
        for (int p = 0; p < 4; ++p) {
          const int g = (tid & 1) * 4 + p;
          *(half8*)(ab + srow * 64 + ((g ^ (srow & 7)) * 8)) = st[c & 1][p];
        }
        __syncthreads();
        if (c + 2 < 16) {
          #pragma unroll
          for (int p = 0; p < 4; ++p)
            st[c & 1][p] = *(const half8*)(abase + (c + 2) * 64 + p * 8);
        }
        #pragma unroll
        for (int ks2 = 0; ks2 < 2; ++ks2) {
          half8 wbf[4];
          #pragma unroll
          for (int n = 0; n < 4; ++n) {
            const int wrow = n * 16 + l15;
            const int g = c * 8 + ks2 * 4 + l4;
            wbf[n] = *(const half8*)(whb + wrow * 1024 + ((g ^ (wrow & 7)) * 8));
          }
          #pragma unroll
          for (int m = 0; m < 2; ++m) {
            const int arow = w * 32 + m * 16 + l15;
            const int ga = ks2 * 4 + l4;
            half8 af = *(const half8*)(ab + arow * 64 + ((ga ^ (arow & 7)) * 8));
            #pragma unroll
            for (int n = 0; n < 4; ++n)
              racc[m][n] = __builtin_amdgcn_mfma_f32_16x16x32_f16(af, wbf[n], racc[m][n], 0, 0, 0);
          }
        }
      }
      // ---- register-local cell update (h writes are agent write-through) ----
      const int t = layer ? (s - 3) : (s - 1);
      _Float16* hw = (layer ? a.h2ring : a.h1ring) + (size_t)((s - 1) & 1) * (B_ * H_);
      #pragma unroll
      for (int m = 0; m < 2; ++m) {
        #pragma unroll
        for (int r = 0; r < 4; ++r) {
          const int brow = row0 + w * 32 + m * 16 + l4 * 4 + r;
          const _Float16* xr = xg + (size_t)brow * 4096 + nb * 64;
          const float gi = racc[m][0][r] + (float)xr[l15];
          const float gf = racc[m][1][r] + (float)xr[16 + l15];
          const float gg = racc[m][2][r] + (float)xr[32 + l15];
          const float go = racc[m][3][r] + (float)xr[48 + l15];
          const float si = fsig(gi), sf = fsig(gf), so = fsig(go);
          const float tg = ftanh(gg);
          const float cn = sf * cst[m * 4 + r] + si * tg;
          const float hn = so * ftanh(cn);
          cst[m * 4 + r] = cn;
          st_h16(hw + (size_t)brow * H_ + hu, (_Float16)hn);
          if (layer == 1 && t == 255) a.hF[(size_t)brow * H_ + hu] = hn;
        }
      }
    }

    if (layer == 0) publish(a.flags, bid, (unsigned)(s + 2));  // h1[t=s-1] visible

    // ================= input-GEMM slice (B in regs) =================
    const bool gAct = layer ? (s >= 2 && s <= 257) : (s <= 255);
    if (gAct) {
      _Float16* og = (layer ? a.xg1ring : a.xg0ring) + (size_t)(s & 1) * (B_ * 4096);
      floatx4 gacc[8] = {};
      if (layer) {
        const _Float16* abase = a.h1ring + (size_t)(s & 1) * (B_ * H_)
                              + (size_t)(row0 + srow) * H_ + scol;
        gemm_tile<16, 1>(abase, bf, ab, gacc);
      } else {
        const float* abase = a.ctx + ((size_t)(row0 + srow) * T_ + s) * I_ + scol;
        gemm_tile<8, 0>(abase, bf, ab, gacc);
      }
      #pragma unroll
      for (int m = 0; m < 8; ++m) {
        #pragma unroll
        for (int r = 0; r < 4; ++r)
          og[(size_t)(row0 + m * 16 + l4 * 4 + r) * 4096 + gcol] = (_Float16)(gacc[m][r] + bv);
      }
    }

    if (layer == 1) publish(a.flags, bid, (unsigned)(s + 2));  // rec+gemm (h1 reads) done
  }
}

__global__ __launch_bounds__(256) void readout(
    const float* __restrict__ hF, const float* __restrict__ Wro,
    const float* __restrict__ bro, float* __restrict__ out) {
  const int b = blockIdx.x;
  const int tid = threadIdx.x;
  float p = 0.f;
  for (int h = tid; h < H_; h += 256) p += hF[(size_t)b * H_ + h] * Wro[h];
  #pragma unroll
  for (int off = 32; off; off >>= 1) p += __shfl_down(p, off, 64);
  __shared__ float red[4];
  if ((tid & 63) == 0) red[tid >> 6] = p;
  __syncthreads();
  if (tid == 0) out[b] = red[0] + red[1] + red[2] + red[3] + bro[0];
}

extern "C" void kernel_launch(void* const* d_in, const int* in_sizes, int n_in,
                              void* d_out, int out_size, void* d_ws, size_t ws_size,
                              hipStream_t stream) {
  const float* init_hidden = (const float*)d_in[0];
  const float* ctx   = (const float*)d_in[1];
  const float* W_ih0 = (const float*)d_in[2];
  const float* W_hh0 = (const float*)d_in[3];
  const float* b_ih0 = (const float*)d_in[4];
  const float* b_hh0 = (const float*)d_in[5];
  const float* W_ih1 = (const float*)d_in[6];
  const float* W_hh1 = (const float*)d_in[7];
  const float* b_ih1 = (const float*)d_in[8];
  const float* b_hh1 = (const float*)d_in[9];
  const float* W_ro  = (const float*)d_in[10];
  const float* b_ro  = (const float*)d_in[11];

  char* ws = (char*)d_ws;
  const size_t MB = 1 << 20;
  _Float16* W0p    = (_Float16*)(ws);                      // 4 MiB
  _Float16* Wh0p   = (_Float16*)(ws + 4 * MB);             // 8 MiB
  _Float16* W1p    = (_Float16*)(ws + 12 * MB);            // 8 MiB
  _Float16* Wh1p   = (_Float16*)(ws + 20 * MB);            // 8 MiB
  float*    bs0    = (float*)(ws + 28 * MB);               // 16 KiB
  float*    bs1    = (float*)(ws + 28 * MB + 16384);       // 16 KiB
  float*    hF     = (float*)(ws + 28 * MB + 32768);       // 1 MiB
  _Float16* h1ring = (_Float16*)(ws + 29 * MB + 32768);    // 1 MiB (2 slots)
  _Float16* h2ring = (_Float16*)(ws + 30 * MB + 32768);    // 1 MiB
  _Float16* xg0    = (_Float16*)(ws + 31 * MB + 32768);    // 4 MiB (2 slots)
  _Float16* xg1    = (_Float16*)(ws + 35 * MB + 32768);    // 4 MiB
  unsigned* flags  = (unsigned*)(ws + 39 * MB + 32768);    // 1 KiB -> end ~39.04 MiB

  hipMemsetAsync(flags, 0, 4096, stream);
  prep_w<<<dim3(2, 4096), 256, 0, stream>>>(W0p, W_ih0, 512);
  prep_w<<<dim3(4, 4096), 256, 0, stream>>>(Wh0p, W_hh0, 1024);
  prep_w<<<dim3(4, 4096), 256, 0, stream>>>(W1p, W_ih1, 1024);
  prep_w<<<dim3(4, 4096), 256, 0, stream>>>(Wh1p, W_hh1, 1024);
  prep_bias<<<dim3(16), 256, 0, stream>>>(bs0, bs1, b_ih0, b_hh0, b_ih1, b_hh1);

  MegaArgs ma;
  ma.ctx = ctx; ma.W0p = W0p; ma.W1p = W1p; ma.Wh0p = Wh0p; ma.Wh1p = Wh1p;
  ma.bs0 = bs0; ma.bs1 = bs1; ma.h1ring = h1ring; ma.h2ring = h2ring;
  ma.xg0ring = xg0; ma.xg1ring = xg1; ma.hF = hF; ma.init = init_hidden;
  ma.flags = flags;
  mega<<<dim3(256), dim3(256), 0, stream>>>(ma);

  readout<<<dim3(256), 256, 0, stream>>>(hF, W_ro, b_ro, (float*)d_out);
}